// Round 6
// baseline (76.775 us; speedup 1.0000x reference)
//
#include <hip/hip_runtime.h>

// VectorQuantizer forward via bf16-split MFMA (fused conversion):
//   x          [64,32,32,64] f32  -> flat [N=65536, D=64]
//   embeddings [D=64, K=512] f32  (codes are COLUMNS)
//   out = x + (q - x),  q = argmin_k ||f - e_k||^2 ;  loss = 1.25*mean((q-x)^2)
//
// argmin_k ||f-e_k||^2 == argmin_k (en2[k] - 2 f.e_k)  (row term r2 common).
// dot = fh*eh + fh*el + fl*eh with bf16 hi/lo splits (|err|~1e-5); rows whose
// approx top-2 gap < TAU get an exact f32 rescan (round-2-identical
// arithmetic). en2b = en2 + 4 keeps the packed metric positive (codes are
// U(-0.05,0.05): |2dot| < 3 at 8.7 sigma) -> u32 bit-monotone packing with
// code index in the low 9 bits == np.argmin first-index tie-break.
//
// vs round 5: x->bf16 conversion fused into vq_main (bit-identical f2bf, so
// MFMA inputs and picks are unchanged), grid 256->1024 blocks (64 rows each)
// for 4 waves/SIMD, one loss atomic per block.

#define N_ROWS 65536
#define DIM 64
#define KCODES 512

typedef short s16x8 __attribute__((ext_vector_type(8)));
typedef float f32x4 __attribute__((ext_vector_type(4)));

// ws byte offsets
#define LOSS_OFF   0
#define EN2_OFF    256
#define EN2B_OFF   2304
#define ET_OFF     4352
#define AFR_OFF    135424

#define TAU 1.2e-3f

__device__ __forceinline__ unsigned short f2bf(float f) {
    unsigned u = __float_as_uint(f);
    return (unsigned short)((u + 0x7fffu + ((u >> 16) & 1u)) >> 16);
}
__device__ __forceinline__ float bf2f(unsigned short h) {
    return __uint_as_float(((unsigned)h) << 16);
}
__device__ __forceinline__ void cvt8(const float* __restrict__ p,
                                     s16x8& hi, s16x8& lo) {
    const float4 v0 = *(const float4*)p;
    const float4 v1 = *(const float4*)(p + 4);
    const float vv[8] = {v0.x, v0.y, v0.z, v0.w, v1.x, v1.y, v1.z, v1.w};
    #pragma unroll
    for (int j = 0; j < 8; ++j) {
        const unsigned short h = f2bf(vv[j]);
        hi[j] = (short)h;
        lo[j] = (short)f2bf(vv[j] - bf2f(h));
    }
}

// ---------------- prep: codebook only (2 blocks x 256 threads)
__global__ void vq_prep(const float* __restrict__ emb, char* __restrict__ ws) {
    const int k = blockIdx.x * 256 + threadIdx.x;   // code 0..511
    if (k == 0) *(double*)(ws + LOSS_OFF) = 0.0;
    float* en2  = (float*)(ws + EN2_OFF);
    float* en2b = (float*)(ws + EN2B_OFF);
    float* eT   = (float*)(ws + ET_OFF);
    uint4* Afr  = (uint4*)(ws + AFR_OFF);
    const int ctg = k >> 4, c = k & 15;
    float s = 0.0f;
    #pragma unroll
    for (int ks = 0; ks < 2; ++ks) {
        #pragma unroll
        for (int g = 0; g < 4; ++g) {
            unsigned short hb[8], lb[8];
            #pragma unroll
            for (int j = 0; j < 8; ++j) {
                const int d = ks * 32 + g * 8 + j;
                const float v = emb[d * KCODES + k];   // coalesced across k
                eT[k * DIM + d] = v;
                s = fmaf(v, v, s);                     // same chain as round-2
                const unsigned short h = f2bf(v);
                hb[j] = h;
                lb[j] = f2bf(v - bf2f(h));
            }
            uint4 H, L;
            H.x = hb[0] | ((unsigned)hb[1] << 16); H.y = hb[2] | ((unsigned)hb[3] << 16);
            H.z = hb[4] | ((unsigned)hb[5] << 16); H.w = hb[6] | ((unsigned)hb[7] << 16);
            L.x = lb[0] | ((unsigned)lb[1] << 16); L.y = lb[2] | ((unsigned)lb[3] << 16);
            L.z = lb[4] | ((unsigned)lb[5] << 16); L.w = lb[6] | ((unsigned)lb[7] << 16);
            const int lane = g * 16 + c;
            Afr[((ctg * 2 + ks) * 2 + 0) * 64 + lane] = H;
            Afr[((ctg * 2 + ks) * 2 + 1) * 64 + lane] = L;
        }
    }
    en2[k] = s;
    en2b[k] = s + 4.0f;
}

// ---------------- main: MFMA distances + argmin + exact fallback + out/loss
__global__ __launch_bounds__(512, 4)
void vq_main(const float* __restrict__ x, const char* __restrict__ ws,
             float* __restrict__ out, double* __restrict__ loss_acc) {
    __shared__ unsigned long long sm_all[4][8][16];
    __shared__ unsigned pick[64];
    __shared__ unsigned short llist[64];
    __shared__ double lpart[8];
    __shared__ int lcnt;

    const int tid = threadIdx.x;
    const int bid = blockIdx.x;
    const int w = __builtin_amdgcn_readfirstlane(tid >> 6);  // wave 0..7 = 64-code group
    const int l = tid & 63;
    if (tid == 0) lcnt = 0;

    // A-fragments: this wave's 64 codes (4 ctiles) x 2 ksteps x {hi,lo}
    const s16x8* Afr = (const s16x8*)(ws + AFR_OFF);
    s16x8 Aeh[4][2], Ael[4][2];
    #pragma unroll
    for (int ct = 0; ct < 4; ++ct) {
        #pragma unroll
        for (int ks = 0; ks < 2; ++ks) {
            const int ctg = w * 4 + ct;
            Aeh[ct][ks] = Afr[((ctg * 2 + ks) * 2 + 0) * 64 + l];
            Ael[ct][ks] = Afr[((ctg * 2 + ks) * 2 + 1) * 64 + l];
        }
    }
    const float* en2b = (const float*)(ws + EN2B_OFF);
    f32x4 enf[4];
    #pragma unroll
    for (int ct = 0; ct < 4; ++ct) {
        const float4 t = *(const float4*)(en2b + w * 64 + ct * 16 + (l >> 4) * 4);
        enf[ct][0] = t.x; enf[ct][1] = t.y; enf[ct][2] = t.z; enf[ct][3] = t.w;
    }
    const int codebase = w * 64 + (l >> 4) * 4;

    __syncthreads();

    #pragma unroll
    for (int bt = 0; bt < 4; ++bt) {
        // B-fragments straight from x, converted in-register (bit-identical
        // to the round-5 staged path).
        const int rowb = bid * 64 + bt * 16 + (l & 15);
        const float* px = x + (size_t)rowb * DIM + (l >> 4) * 8;
        s16x8 bh0, bl0, bh1, bl1;
        cvt8(px, bh0, bl0);
        cvt8(px + 32, bh1, bl1);

        f32x4 acc[4];
        #pragma unroll
        for (int ct = 0; ct < 4; ++ct) {
            f32x4 a = {0.f, 0.f, 0.f, 0.f};
            a = __builtin_amdgcn_mfma_f32_16x16x32_bf16(Aeh[ct][0], bh0, a, 0, 0, 0);
            a = __builtin_amdgcn_mfma_f32_16x16x32_bf16(Aeh[ct][1], bh1, a, 0, 0, 0);
            a = __builtin_amdgcn_mfma_f32_16x16x32_bf16(Ael[ct][0], bh0, a, 0, 0, 0);
            a = __builtin_amdgcn_mfma_f32_16x16x32_bf16(Ael[ct][1], bh1, a, 0, 0, 0);
            a = __builtin_amdgcn_mfma_f32_16x16x32_bf16(Aeh[ct][0], bl0, a, 0, 0, 0);
            a = __builtin_amdgcn_mfma_f32_16x16x32_bf16(Aeh[ct][1], bl1, a, 0, 0, 0);
            acc[ct] = a;
        }
        // min1/min2 over this lane's 16 (code, value) pairs, packed:
        // high 23 bits = f32 bits of (en2+4-2dot) masked, low 9 bits = code.
        unsigned m1 = 0xFFFFFFFFu, m2 = 0xFFFFFFFFu;
        #pragma unroll
        for (int ct = 0; ct < 4; ++ct) {
            #pragma unroll
            for (int rg = 0; rg < 4; ++rg) {
                const float m = fmaf(-2.0f, acc[ct][rg], enf[ct][rg]);
                const unsigned u = (__float_as_uint(m) & 0xFFFFFE00u)
                                 | (unsigned)(codebase + ct * 16 + rg);
                const unsigned hi = m1 > u ? m1 : u;
                m1 = m1 < u ? m1 : u;
                m2 = m2 < hi ? m2 : hi;
            }
        }
        #pragma unroll
        for (int mask = 16; mask <= 32; mask <<= 1) {
            const unsigned o1 = __shfl_xor(m1, mask);
            const unsigned o2 = __shfl_xor(m2, mask);
            const unsigned hi  = m1 > o1 ? m1 : o1;
            const unsigned lo2 = m2 < o2 ? m2 : o2;
            m1 = m1 < o1 ? m1 : o1;
            m2 = hi < lo2 ? hi : lo2;
        }
        if (l < 16) sm_all[bt][w][l] = ((unsigned long long)m1 << 32) | m2;
    }
    __syncthreads();

    // combine the 8 waves' results per row; flag near-ties for exact rescan
    if (tid < 64) {
        const int bt = tid >> 4, c = tid & 15;
        unsigned long long p = sm_all[bt][0][c];
        unsigned m1 = (unsigned)(p >> 32), m2 = (unsigned)p;
        #pragma unroll
        for (int w2 = 1; w2 < 8; ++w2) {
            p = sm_all[bt][w2][c];
            const unsigned a1 = (unsigned)(p >> 32), a2 = (unsigned)p;
            const unsigned hi  = m1 > a1 ? m1 : a1;
            const unsigned lo2 = m2 < a2 ? m2 : a2;
            m1 = m1 < a1 ? m1 : a1;
            m2 = hi < lo2 ? hi : lo2;
        }
        pick[tid] = m1 & 0x1FFu;
        const float f1 = __uint_as_float(m1 & 0xFFFFFE00u);
        const float f2 = __uint_as_float(m2 & 0xFFFFFE00u);
        if (f2 - f1 < TAU) {
            const int idx = atomicAdd(&lcnt, 1);
            llist[idx] = (unsigned short)tid;
        }
    }
    __syncthreads();

    // exact f32 fallback (round-2-identical arithmetic), one wave per row
    {
        const float* eT  = (const float*)(ws + ET_OFF);
        const float* en2 = (const float*)(ws + EN2_OFF);
        const int nfb = lcnt;
        for (int i = w; i < nfb; i += 8) {
            const int r = llist[i];
            const int grow = bid * 64 + r;
            const float4* xr = (const float4*)(x + (size_t)grow * DIM);
            float4 f[16];
            #pragma unroll
            for (int j = 0; j < 16; ++j) f[j] = xr[j];
            float4 a4 = make_float4(0.f, 0.f, 0.f, 0.f);
            #pragma unroll
            for (int j = 0; j < 16; ++j) {
                a4.x = fmaf(f[j].x, f[j].x, a4.x);
                a4.y = fmaf(f[j].y, f[j].y, a4.y);
                a4.z = fmaf(f[j].z, f[j].z, a4.z);
                a4.w = fmaf(f[j].w, f[j].w, a4.w);
            }
            const float r2 = (a4.x + a4.y) + (a4.z + a4.w);
            unsigned long long best = 0xFFFFFFFFFFFFFFFFull;
            #pragma unroll 2
            for (int c8 = 0; c8 < 8; ++c8) {
                const int k = l * 8 + c8;
                const float4* ek = (const float4*)(eT + k * DIM);
                float4 acc4 = make_float4(0.f, 0.f, 0.f, 0.f);
                #pragma unroll
                for (int j = 0; j < 16; ++j) {
                    const float4 e = ek[j];
                    acc4.x = fmaf(f[j].x, e.x, acc4.x);
                    acc4.y = fmaf(f[j].y, e.y, acc4.y);
                    acc4.z = fmaf(f[j].z, e.z, acc4.z);
                    acc4.w = fmaf(f[j].w, e.w, acc4.w);
                }
                const float dot = (acc4.x + acc4.y) + (acc4.z + acc4.w);
                const float s = (r2 + en2[k]) - 2.0f * dot;
                const unsigned long long pk =
                    ((unsigned long long)__float_as_uint(s) << 32) | (unsigned)k;
                if (pk < best) best = pk;   // ascending k + strict < == np.argmin
            }
            #pragma unroll
            for (int mask = 1; mask <= 32; mask <<= 1) {
                const unsigned long long o = __shfl_xor(best, mask);
                if (o < best) best = o;
            }
            if (l == 0) pick[r] = (unsigned)best & 0x1FFu;
        }
    }
    __syncthreads();

    // out = x + (q - x) and loss
    {
        const float* eT = (const float*)(ws + ET_OFF);
        const int r = tid >> 3, c8 = tid & 7;
        const int grow = bid * 64 + r;
        const float4* xr = (const float4*)(x + (size_t)grow * DIM) + c8 * 2;
        const float4* qr = (const float4*)(eT + pick[r] * DIM) + c8 * 2;
        float4* orow = ((float4*)out) + (size_t)grow * 16 + c8 * 2;
        float lsum = 0.0f;
        #pragma unroll
        for (int j = 0; j < 2; ++j) {
            const float4 q = qr[j], xv = xr[j];
            float4 o; float dx;
            dx = q.x - xv.x; o.x = xv.x + dx; lsum = fmaf(dx, dx, lsum);
            dx = q.y - xv.y; o.y = xv.y + dx; lsum = fmaf(dx, dx, lsum);
            dx = q.z - xv.z; o.z = xv.z + dx; lsum = fmaf(dx, dx, lsum);
            dx = q.w - xv.w; o.w = xv.w + dx; lsum = fmaf(dx, dx, lsum);
            orow[j] = o;
        }
        double dl = (double)lsum;
        #pragma unroll
        for (int off = 32; off > 0; off >>= 1) dl += __shfl_down(dl, off);
        if (l == 0) lpart[w] = dl;
    }
    __syncthreads();
    if (tid == 0) {
        double s = lpart[0];
        #pragma unroll
        for (int t = 1; t < 8; ++t) s += lpart[t];
        atomicAdd(loss_acc, s);
    }
}

__global__ void vq_fin(const double* __restrict__ loss_acc, float* __restrict__ out) {
    if (threadIdx.x == 0)
        out[N_ROWS * DIM] = (float)(1.25 * loss_acc[0] * (1.0 / (double)(N_ROWS * DIM)));
}

extern "C" void kernel_launch(void* const* d_in, const int* in_sizes, int n_in,
                              void* d_out, int out_size, void* d_ws, size_t ws_size,
                              hipStream_t stream) {
    const float* x   = (const float*)d_in[0];
    const float* emb = (const float*)d_in[1];
    float* out = (float*)d_out;
    char*  ws  = (char*)d_ws;

    vq_prep<<<2, 256, 0, stream>>>(emb, ws);
    vq_main<<<1024, 512, 0, stream>>>(x, ws, out, (double*)(ws + LOSS_OFF));
    vq_fin<<<1, 1, 0, stream>>>((const double*)(ws + LOSS_OFF), out);
}